// Round 17
// baseline (5281.322 us; speedup 1.0000x reference)
//
#include <hip/hip_runtime.h>
#include <hip/hip_bf16.h>
#include <math.h>

typedef __bf16 bf16;
typedef __bf16 bf16x2 __attribute__((ext_vector_type(2)));
typedef __bf16 bf16x8 __attribute__((ext_vector_type(8)));
typedef float  f32x4  __attribute__((ext_vector_type(4)));

#define B_  32
#define S_  512
#define H_  768
#define NH_ 12
#define DH_ 64
#define FF_ 3072
#define L_  12
#define M_  (B_*S_)
#define QKV_ 2304   // packed q|k|v row stride

// padded LDS strides (attention V/P tiles; K XOR-swizzled, unpadded)
#define VST 516
#define PST 68

// ---- async global->LDS, 16B per lane; lds base must be wave-uniform ----
__device__ __forceinline__ void gload16(const bf16* g, bf16* l) {
  __builtin_amdgcn_global_load_lds(
      (const __attribute__((address_space(1))) void*)g,
      (__attribute__((address_space(3))) void*)l, 16, 0, 0);
}

// ---- fast exact-GELU: Abramowitz-Stegun 7.1.26 erf, |err| < 1.5e-7 ----
__device__ __forceinline__ float fast_gelu(float x) {
  float z = x * 0.70710678118f;
  float s = fabsf(z);
  float t = __builtin_amdgcn_rcpf(1.0f + 0.3275911f * s);
  float p = t*(0.254829592f + t*(-0.284496736f + t*(1.421413741f +
            t*(-1.453152027f + t*1.061405429f))));
  float e = p * __expf(-s*s);          // = 1 - erf(s)
  float erfv = copysignf(1.0f - e, z);
  return 0.5f * x * (1.0f + erfv);
}

// =================== 128x128 GEMM, 8 waves, T3-minimum double-buffer pipeline ===================
// r17: STAGE(buf^1, t+1) issued BEFORE computing tile t; ONE __syncthreads per
// tile placed AFTER the MFMA (its vmcnt(0) drain then lands the prefetch that
// had the whole ds_read+MFMA phase in flight). Replaces the stage;sync;compute;
// sync structure whose first barrier drained vmcnt immediately (zero overlap).
// LDS 64 KB -> 2 blocks/CU (~16 waves, same as r16's achieved 56%).
__global__ __launch_bounds__(512, 4) void gemm128(
    const bf16* __restrict__ A, const bf16* __restrict__ Bt,
    const float* __restrict__ bias, void* __restrict__ outp,
    int N, int K, int tiles_n, int epi)
{
  __shared__ bf16 sm[2][2][128*64];   // [buf][A|B] : 64 KB
  const int tid  = threadIdx.x;
  const int lane = tid & 63, wid = tid >> 6;
  const int wr = wid >> 2, wc = wid & 3;          // 2 x 4 wave grid, 64x32 per wave
  const int lrow = lane & 15, kgrp = lane >> 4;

  // bijective XCD swizzle (m204)
  const int nwg = gridDim.x, orig = blockIdx.x;
  const int qc = nwg >> 3, rc = nwg & 7;
  const int xcd = orig & 7, lin = orig >> 3;
  const int wg = (xcd < rc ? xcd*(qc+1) : rc*(qc+1) + (xcd-rc)*qc) + lin;
  const int tm = wg / tiles_n, tn = wg % tiles_n;
  const size_t m0 = (size_t)tm * 128, n0 = (size_t)tn * 128;
  const int KT = K >> 6;

  const bf16* Ab = A  + m0 * K;
  const bf16* Bb = Bt + n0 * K;

  auto stage = [&](const bf16* gbase, bf16* ldsbase, int kt) {
#pragma unroll
    for (int j = 0; j < 2; ++j) {
      int lin2  = j*512 + tid;
      int prow  = lin2 >> 3;
      int pslot = lin2 & 7;
      int lslot = pslot ^ (prow & 7);
      const bf16* src = gbase + (size_t)prow * K + (size_t)kt*64 + lslot*8;
      bf16* dst = ldsbase + (size_t)(j*512 + (wid<<6))*8;
      gload16(src, dst);
    }
  };

  f32x4 acc[4][2] = {};

  // prologue: tile 0 into buf 0, drain, barrier
  stage(Ab, &sm[0][0][0], 0);
  stage(Bb, &sm[0][1][0], 0);
  __syncthreads();

  int cur = 0;
  for (int t = 0; t < KT; ++t) {
    if (t + 1 < KT) {                       // issue next-tile prefetch (stays in flight)
      stage(Ab, &sm[cur^1][0][0], t+1);
      stage(Bb, &sm[cur^1][1][0], t+1);
    }
    const bf16* As = &sm[cur][0][0];
    const bf16* Bs = &sm[cur][1][0];
#pragma unroll
    for (int kk = 0; kk < 2; ++kk) {
      bf16x8 a[4], b[2];
#pragma unroll
      for (int m = 0; m < 4; ++m) {
        int row  = wr*64 + m*16 + lrow;
        int slot = (kk*4 + kgrp) ^ (lrow & 7);
        a[m] = *(const bf16x8*)&As[row*64 + slot*8];
      }
#pragma unroll
      for (int n = 0; n < 2; ++n) {
        int row  = wc*32 + n*16 + lrow;
        int slot = (kk*4 + kgrp) ^ (lrow & 7);
        b[n] = *(const bf16x8*)&Bs[row*64 + slot*8];
      }
#pragma unroll
      for (int m = 0; m < 4; ++m)
#pragma unroll
        for (int n = 0; n < 2; ++n)
          acc[m][n] = __builtin_amdgcn_mfma_f32_16x16x32_bf16(a[m], b[n], acc[m][n], 0, 0, 0);
    }
    __syncthreads();                        // drains vmcnt -> buf^1 ready; readers done with cur
    cur ^= 1;
  }

#pragma unroll
  for (int m = 0; m < 4; ++m)
#pragma unroll
    for (int n = 0; n < 2; ++n) {
      int col = (int)n0 + wc*32 + n*16 + lrow;
      float bv = bias[col];
#pragma unroll
      for (int r = 0; r < 4; ++r) {
        int row = (int)m0 + wr*64 + m*16 + kgrp*4 + r;
        float x = acc[m][n][r] + bv;
        size_t idx = (size_t)row * N + col;
        if (epi == 1)      ((float*)outp)[idx] = x;
        else if (epi == 0) ((bf16*)outp)[idx]  = (bf16)x;
        else               ((bf16*)outp)[idx]  = (bf16)fast_gelu(x);
      }
    }
}

// ---------------- fused per-layer weight prep: 6 transposes + bias pack ----------------
__global__ __launch_bounds__(256) void weight_prep(
    const float* __restrict__ Wq, const float* __restrict__ Wk,
    const float* __restrict__ Wv, const float* __restrict__ Wo,
    const float* __restrict__ Wi, const float* __restrict__ Wf,
    const float* __restrict__ bq, const float* __restrict__ bk,
    const float* __restrict__ bv,
    bf16* __restrict__ wqkv, bf16* __restrict__ wot,
    bf16* __restrict__ wit,  bf16* __restrict__ wft,
    float* __restrict__ qkbias)
{
  int bid = blockIdx.x;
  if (bid >= 1728) {
    int i = (bid - 1728)*256 + threadIdx.x;
    if (i < QKV_)
      qkbias[i] = (i < 768) ? bq[i] : (i < 1536 ? bk[i-768] : bv[i-1536]);
    return;
  }
  const float* W; bf16* Wt; int K, N, t;
  if (bid < 576) {
    K = 768; N = 768;
    if      (bid < 144) { W = Wq; Wt = wqkv;             t = bid; }
    else if (bid < 288) { W = Wk; Wt = wqkv + 768*768;   t = bid - 144; }
    else if (bid < 432) { W = Wv; Wt = wqkv + 2*768*768; t = bid - 288; }
    else                { W = Wo; Wt = wot;              t = bid - 432; }
  } else if (bid < 1152) { W = Wi; Wt = wit; K = 768;  N = 3072; t = bid - 576; }
  else                   { W = Wf; Wt = wft; K = 3072; N = 768;  t = bid - 1152; }
  const int kt = K >> 6;
  const int k0 = (t % kt)*64, n0 = (t / kt)*64;

  __shared__ bf16 T[64][65];
  int tx = threadIdx.x & 63, ty = threadIdx.x >> 6;
#pragma unroll
  for (int j = 0; j < 16; ++j) {
    int kk = j*4 + ty;
    T[kk][tx] = (bf16)W[(size_t)(k0+kk)*N + n0 + tx];
  }
  __syncthreads();
#pragma unroll
  for (int j = 0; j < 16; ++j) {
    int nn = j*4 + ty;
    Wt[(size_t)(n0+nn)*K + k0 + tx] = T[tx][nn];
  }
}

// ---------------- block reductions ----------------
__device__ __forceinline__ void block_sum2(float& a, float& b, float* red) {
  int lane = threadIdx.x & 63, wid = threadIdx.x >> 6;
  for (int o = 32; o > 0; o >>= 1) { a += __shfl_xor(a, o); b += __shfl_xor(b, o); }
  if (lane == 0) { red[wid*2] = a; red[wid*2+1] = b; }
  __syncthreads();
  a = red[0] + red[2] + red[4] + red[6];
  b = red[1] + red[3] + red[5] + red[7];
  __syncthreads();
}

// ---------------- embedding + LN (bf16 residual out) ----------------
__global__ __launch_bounds__(256) void embed_ln(
    const int* __restrict__ ids, const float* __restrict__ we,
    const float* __restrict__ pe, const float* __restrict__ te,
    const float* __restrict__ gs, const float* __restrict__ gb,
    bf16* __restrict__ hb)
{
  __shared__ float red[8];
  int row = blockIdx.x;
  int s = row & (S_-1);
  int id = ids[row];
  int t = threadIdx.x;
  float x[3], sum = 0.f, sq = 0.f;
#pragma unroll
  for (int j = 0; j < 3; ++j) {
    int c = t + j*256;
    float v = we[(size_t)id*H_ + c] + pe[(size_t)s*H_ + c] + te[c];
    x[j] = v; sum += v; sq += v*v;
  }
  block_sum2(sum, sq, red);
  float mean = sum * (1.f/H_);
  float var  = sq  * (1.f/H_) - mean*mean;
  float rstd = rsqrtf(fmaxf(var, 0.f) + 1e-12f);
#pragma unroll
  for (int j = 0; j < 3; ++j) {
    int c = t + j*256;
    float y = (x[j]-mean)*rstd*gs[c] + gb[c];
    hb[(size_t)row*H_ + c] = (bf16)y;
  }
}

// ---------------- residual add + LN, all-bf16 streams ----------------
__global__ __launch_bounds__(256) void ln_res2(
    const bf16* __restrict__ t16, const bf16* __restrict__ res,
    const float* __restrict__ gs, const float* __restrict__ gb,
    bf16* __restrict__ out)
{
  __shared__ float red[2][2][2];
  int t = threadIdx.x;
  int rloc = t & 127, rsel = t >> 7, wir = (t >> 6) & 1;
  size_t row = (size_t)blockIdx.x*2 + rsel;
  const bf16* tp = t16 + row*H_;
  const bf16* rp = res + row*H_;
  float x[6];
  float sum = 0.f, sq = 0.f;
#pragma unroll
  for (int j = 0; j < 3; ++j) {
    int c = rloc*2 + j*256;
    bf16x2 a = *(const bf16x2*)&tp[c];
    bf16x2 b = *(const bf16x2*)&rp[c];
    float v0 = (float)a[0] + (float)b[0];
    float v1 = (float)a[1] + (float)b[1];
    x[j*2] = v0; x[j*2+1] = v1;
    sum += v0 + v1; sq += v0*v0 + v1*v1;
  }
  for (int o = 32; o > 0; o >>= 1) { sum += __shfl_xor(sum, o); sq += __shfl_xor(sq, o); }
  if ((t & 63) == 0) { red[rsel][wir][0] = sum; red[rsel][wir][1] = sq; }
  __syncthreads();
  sum = red[rsel][0][0] + red[rsel][1][0];
  sq  = red[rsel][0][1] + red[rsel][1][1];
  float mean = sum * (1.f/H_);
  float var  = sq  * (1.f/H_) - mean*mean;
  float rstd = rsqrtf(fmaxf(var, 0.f) + 1e-12f);
  bf16* op = out + row*H_;
#pragma unroll
  for (int j = 0; j < 3; ++j) {
    int c = rloc*2 + j*256;
    bf16x2 o2;
    o2[0] = (bf16)((x[j*2]   - mean)*rstd*gs[c]   + gb[c]);
    o2[1] = (bf16)((x[j*2+1] - mean)*rstd*gs[c+1] + gb[c+1]);
    *(bf16x2*)&op[c] = o2;
  }
}

// ---------------- fused attention: persistent balanced grid (r15, frozen) ----------------
__global__ __launch_bounds__(512, 2) void attn_kernel(
    const bf16* __restrict__ qkv, const float* __restrict__ mask,
    bf16* __restrict__ ctx)
{
  __shared__ bf16 Kl[S_*64];       // 65536 B, XOR-swizzled 16B slots
  __shared__ bf16 Vt[DH_*VST];     // 66048 B
  __shared__ float mk[S_];         //  2048 B
  __shared__ bf16 Pl[8][16*PST];   // 17408 B   total ~151 KB
  int tid = threadIdx.x, lane = tid & 63, wid = tid >> 6;
  int lrow = lane & 15, kgrp = lane >> 4;
  int cur_head = -1;

  bf16x8 onesv;
#pragma unroll
  for (int i = 0; i < 8; ++i) onesv[i] = (bf16)1.0f;

  for (int u = 0; u < 6; ++u) {
    int unit = blockIdx.x*6 + u;
    int hh = unit >> 2, pass = unit & 3;
    int b = hh / NH_, h = hh % NH_;
    const bf16* Qb = qkv + (size_t)(b*S_)*QKV_ + h*DH_;

    if (hh != cur_head) {
      __syncthreads();             // all waves done with prev head's tiles
      const bf16* Kb = qkv + (size_t)(b*S_)*QKV_ + H_   + h*DH_;
      const bf16* Vb = qkv + (size_t)(b*S_)*QKV_ + 2*H_ + h*DH_;
#pragma unroll
      for (int it = 0; it < 8; ++it) {
        int lin   = it*512 + tid;
        int prow  = lin >> 3;
        int pslot = lin & 7;
        int lslot = pslot ^ (prow & 7);
        gload16(&Kb[(size_t)prow*QKV_ + lslot*8],
                &Kl[(size_t)(it*512 + (wid<<6))*8]);
      }
      for (int it = 0; it < 8; ++it) {
        int slot = it*512 + tid;
        int s = slot >> 3, c8 = (slot & 7)*8;
        bf16x8 v = *(const bf16x8*)&Vb[(size_t)s*QKV_ + c8];
#pragma unroll
        for (int i = 0; i < 8; ++i) Vt[(c8+i)*VST + s] = v[i];
      }
      mk[tid] = mask[b*S_ + tid];  // 512 threads == S
      cur_head = hh;
      __syncthreads();             // drains vmcnt (gload16) + lgkm
    }

    int q0 = pass*128 + wid*16;
    bf16x8 qa[2];
#pragma unroll
    for (int kc = 0; kc < 2; ++kc) {
      qa[kc] = *(const bf16x8*)&Qb[(size_t)(q0 + lrow)*QKV_ + kc*32 + kgrp*8];
#pragma unroll
      for (int i = 0; i < 8; ++i)
        qa[kc][i] = (bf16)((float)qa[kc][i] * 0.125f);   // exact pow2
    }
    f32x4 O[4] = {};
    f32x4 O5 = {};                 // softmax denominator accumulator
    float mrun[4];
#pragma unroll
    for (int r = 0; r < 4; ++r) mrun[r] = -1e30f;

#pragma unroll 2
    for (int c0 = 0; c0 < S_; c0 += 64) {
      f32x4 Sf[4] = {};
      __builtin_amdgcn_s_setprio(1);
#pragma unroll
      for (int kc = 0; kc < 2; ++kc)
#pragma unroll
        for (int sn = 0; sn < 4; ++sn) {
          int row  = c0 + sn*16 + lrow;
          int slot = (kc*4 + kgrp) ^ (lrow & 7);
          bf16x8 kbv = *(const bf16x8*)&Kl[(size_t)row*64 + slot*8];
          Sf[sn] = __builtin_amdgcn_mfma_f32_16x16x32_bf16(qa[kc], kbv, Sf[sn], 0, 0, 0);
        }
      __builtin_amdgcn_s_setprio(0);

      float lm[4];
#pragma unroll
      for (int r = 0; r < 4; ++r)
        lm[r] = fmaxf(fmaxf(Sf[0][r], Sf[1][r]), fmaxf(Sf[2][r], Sf[3][r]));
      bool small = (lm[0] <= mrun[0]+8.f) && (lm[1] <= mrun[1]+8.f) &&
                   (lm[2] <= mrun[2]+8.f) && (lm[3] <= mrun[3]+8.f);
      bool skip = __all(small);
      float newm[4];
      if (skip) {
#pragma unroll
        for (int r = 0; r < 4; ++r) newm[r] = mrun[r];
      } else {
        float cmax[4];
#pragma unroll
        for (int r = 0; r < 4; ++r) cmax[r] = lm[r];
        for (int o = 1; o < 16; o <<= 1)
#pragma unroll
          for (int r = 0; r < 4; ++r) cmax[r] = fmaxf(cmax[r], __shfl_xor(cmax[r], o));
#pragma unroll
        for (int r = 0; r < 4; ++r) {
          newm[r] = fmaxf(mrun[r], cmax[r]);
          float fr = __expf(mrun[r] - newm[r]);
#pragma unroll
          for (int on = 0; on < 4; ++on) O[on][r] *= fr;
          O5[r] *= fr;
          mrun[r] = newm[r];
        }
      }
#pragma unroll
      for (int sn = 0; sn < 4; ++sn) {
        float mkv = mk[c0 + sn*16 + lrow];
#pragma unroll
        for (int r = 0; r < 4; ++r) {
          float e = __expf(Sf[sn][r] - newm[r]) * mkv;
          Pl[wid][(kgrp*4 + r)*PST + sn*16 + lrow] = (bf16)e;
        }
      }
      __builtin_amdgcn_s_setprio(1);
#pragma unroll
      for (int kc = 0; kc < 2; ++kc) {
        bf16x8 pa = *(const bf16x8*)&Pl[wid][lrow*PST + kc*32 + kgrp*8];
#pragma unroll
        for (int on = 0; on < 4; ++on) {
          bf16x8 vv = *(const bf16x8*)&Vt[(on*16 + lrow)*VST + c0 + kc*32 + kgrp*8];
          O[on] = __builtin_amdgcn_mfma_f32_16x16x32_bf16(pa, vv, O[on], 0, 0, 0);
        }
        O5 = __builtin_amdgcn_mfma_f32_16x16x32_bf16(pa, onesv, O5, 0, 0, 0);
      }
      __builtin_amdgcn_s_setprio(0);
    }
#pragma unroll
    for (int on = 0; on < 4; ++on)
#pragma unroll
      for (int r = 0; r < 4; ++r) {
        float val = O[on][r] / fmaxf(O5[r], 1e-9f);
        int q = q0 + kgrp*4 + r;
        ctx[(size_t)(b*S_ + q)*H_ + h*DH_ + on*16 + lrow] = (bf16)val;
      }
  }
}

// ---------------- pooling: partial (B*8 blocks, bf16 input) + final ----------------
__global__ __launch_bounds__(256) void pool_partial(
    const bf16* __restrict__ hb, const float* __restrict__ mask,
    float* __restrict__ part)
{
  int b = blockIdx.x >> 3, ch = blockIdx.x & 7;
  int t = threadIdx.x;
  float a0 = 0.f, a1 = 0.f, a2 = 0.f;
  for (int s = ch*64; s < ch*64 + 64; ++s) {
    float m = mask[b*S_ + s];
    const bf16* hp = &hb[((size_t)b*S_ + s)*H_];
    a0 += (float)hp[t]*m; a1 += (float)hp[t+256]*m; a2 += (float)hp[t+512]*m;
  }
  float* pp = &part[(size_t)(b*8 + ch)*H_];
  pp[t] = a0; pp[t+256] = a1; pp[t+512] = a2;
}

__global__ __launch_bounds__(256) void pool_final(
    const float* __restrict__ part, const float* __restrict__ mask,
    float* __restrict__ out)
{
  __shared__ float red[8];
  int b = blockIdx.x, t = threadIdx.x;
  float s0 = 0.f, s1 = 0.f, s2 = 0.f;
#pragma unroll
  for (int ch = 0; ch < 8; ++ch) {
    const float* pp = &part[(size_t)(b*8 + ch)*H_];
    s0 += pp[t]; s1 += pp[t+256]; s2 += pp[t+512];
  }
  float msum = mask[b*S_ + t] + mask[b*S_ + 256 + t];
  float dummy = 0.f;
  block_sum2(msum, dummy, red);
  float inv = 1.f / fmaxf(msum, 1e-6f);
  s0 *= inv; s1 *= inv; s2 *= inv;
  float nrm = s0*s0 + s1*s1 + s2*s2;
  dummy = 0.f;
  block_sum2(nrm, dummy, red);
  float rn = 1.f / fmaxf(sqrtf(nrm), 1e-12f);
  out[b*H_ + t]       = s0*rn;
  out[b*H_ + t + 256] = s1*rn;
  out[b*H_ + t + 512] = s2*rn;
}

// ---------------- host driver ----------------
extern "C" void kernel_launch(void* const* d_in, const int* in_sizes, int n_in,
                              void* d_out, int out_size, void* d_ws, size_t ws_size,
                              hipStream_t stream)
{
  const int*   ids  = (const int*)  d_in[0];
  const float* mask = (const float*)d_in[1];
  const float* we   = (const float*)d_in[2];
  const float* pe   = (const float*)d_in[3];
  const float* te   = (const float*)d_in[4];
  const float* les  = (const float*)d_in[5];
  const float* leb  = (const float*)d_in[6];
  const float* Wq   = (const float*)d_in[7];
  const float* bq   = (const float*)d_in[8];
  const float* Wk   = (const float*)d_in[9];
  const float* bk   = (const float*)d_in[10];
  const float* Wv   = (const float*)d_in[11];
  const float* bv   = (const float*)d_in[12];
  const float* Wo   = (const float*)d_in[13];
  const float* bo   = (const float*)d_in[14];
  const float* l1s  = (const float*)d_in[15];
  const float* l1b  = (const float*)d_in[16];
  const float* Wi   = (const float*)d_in[17];
  const float* bi   = (const float*)d_in[18];
  const float* Wf   = (const float*)d_in[19];
  const float* bfp  = (const float*)d_in[20];
  const float* l2s  = (const float*)d_in[21];
  const float* l2b  = (const float*)d_in[22];

  char* p = (char*)d_ws;
  auto alloc = [&](size_t bytes) { char* q = p; p += (bytes + 255) & ~(size_t)255; return q; };
  bf16*  wqkv = (bf16*) alloc((size_t)QKV_*H_*2);
  bf16*  wot  = (bf16*) alloc((size_t)H_*H_*2);
  bf16*  wit  = (bf16*) alloc((size_t)H_*FF_*2);
  bf16*  wft  = (bf16*) alloc((size_t)H_*FF_*2);
  float* qkbias=(float*)alloc((size_t)QKV_*4);
  bf16*  hb   = (bf16*) alloc((size_t)M_*H_*2);
  bf16*  ab   = (bf16*) alloc((size_t)M_*H_*2);
  bf16*  tmpb = (bf16*) alloc((size_t)M_*H_*2);
  bf16*  qkvb = (bf16*) alloc((size_t)M_*QKV_*2);
  bf16*  cxb  = (bf16*) alloc((size_t)M_*H_*2);
  bf16*  inb  = (bf16*) alloc((size_t)M_*FF_*2);
  float* part = (float*)alloc((size_t)B_*8*H_*4);

  embed_ln<<<M_, 256, 0, stream>>>(ids, we, pe, te, les, leb, hb);

  for (int l = 0; l < L_; ++l) {
    size_t wsq = (size_t)l*H_*H_;
    weight_prep<<<1737, 256, 0, stream>>>(
        Wq + wsq, Wk + wsq, Wv + wsq, Wo + wsq,
        Wi + (size_t)l*H_*FF_, Wf + (size_t)l*FF_*H_,
        bq + l*H_, bk + l*H_, bv + l*H_,
        wqkv, wot, wit, wft, qkbias);

    gemm128<<<128*(QKV_/128), 512, 0, stream>>>(hb,  wqkv, qkbias,      qkvb, QKV_, H_,  QKV_/128, 0);
    attn_kernel<<<256, 512, 0, stream>>>(qkvb, mask, cxb);
    gemm128<<<128*(H_/128),  512, 0, stream>>>(cxb, wot, bo  + l*H_,  tmpb, H_,  H_,  H_/128,  0);
    ln_res2<<<M_/2, 256, 0, stream>>>(tmpb, hb, l1s + l*H_, l1b + l*H_, ab);
    gemm128<<<128*(FF_/128), 512, 0, stream>>>(ab,  wit, bi  + l*FF_, inb,  FF_, H_,  FF_/128, 2);
    gemm128<<<128*(H_/128),  512, 0, stream>>>(inb, wft, bfp + l*H_,  tmpb, H_,  FF_, H_/128,  0);
    ln_res2<<<M_/2, 256, 0, stream>>>(tmpb, ab, l2s + l*H_, l2b + l*H_, hb);
  }

  pool_partial<<<B_*8, 256, 0, stream>>>(hb, mask, part);
  pool_final<<<B_, 256, 0, stream>>>(part, mask, (float*)d_out);
}

// Round 18
// 4702.654 us; speedup vs baseline: 1.1231x; 1.1231x over previous
//
#include <hip/hip_runtime.h>
#include <hip/hip_bf16.h>
#include <math.h>

typedef __bf16 bf16;
typedef __bf16 bf16x2 __attribute__((ext_vector_type(2)));
typedef __bf16 bf16x8 __attribute__((ext_vector_type(8)));
typedef float  f32x4  __attribute__((ext_vector_type(4)));

#define B_  32
#define S_  512
#define H_  768
#define NH_ 12
#define DH_ 64
#define FF_ 3072
#define L_  12
#define M_  (B_*S_)
#define QKV_ 2304   // packed q|k|v row stride

// padded LDS strides (attention V/P tiles; K XOR-swizzled, unpadded)
#define VST 516
#define PST 68

// ---- async global->LDS, 16B per lane; lds base must be wave-uniform ----
__device__ __forceinline__ void gload16(const bf16* g, bf16* l) {
  __builtin_amdgcn_global_load_lds(
      (const __attribute__((address_space(1))) void*)g,
      (__attribute__((address_space(3))) void*)l, 16, 0, 0);
}

// ---- fast exact-GELU: Abramowitz-Stegun 7.1.26 erf, |err| < 1.5e-7 ----
__device__ __forceinline__ float fast_gelu(float x) {
  float z = x * 0.70710678118f;
  float s = fabsf(z);
  float t = __builtin_amdgcn_rcpf(1.0f + 0.3275911f * s);
  float p = t*(0.254829592f + t*(-0.284496736f + t*(1.421413741f +
            t*(-1.453152027f + t*1.061405429f))));
  float e = p * __expf(-s*s);          // = 1 - erf(s)
  float erfv = copysignf(1.0f - e, z);
  return 0.5f * x * (1.0f + erfv);
}

// =================== 128x128 GEMM, 8 waves (r16 known-good, FROZEN) ===================
// Structural plateau confirmed 3 ways: 256x128 tile (r14), explicit double-buffer
// (r17), 8-phase ports (r2-r4) all regress — TLP from 4 co-resident blocks beats
// intra-block pipelining for this 2-phase structure (guide m99/m100/m132 agree).
__global__ __launch_bounds__(512, 4) void gemm128(
    const bf16* __restrict__ A, const bf16* __restrict__ Bt,
    const float* __restrict__ bias, void* __restrict__ outp,
    int N, int K, int tiles_n, int epi)
{
  __shared__ bf16 As[128*64];   // 16 KB
  __shared__ bf16 Bs[128*64];   // 16 KB
  const int tid  = threadIdx.x;
  const int lane = tid & 63, wid = tid >> 6;
  const int wr = wid >> 2, wc = wid & 3;          // 2 x 4 wave grid, 64x32 per wave
  const int lrow = lane & 15, kgrp = lane >> 4;

  // bijective XCD swizzle (m204)
  const int nwg = gridDim.x, orig = blockIdx.x;
  const int qc = nwg >> 3, rc = nwg & 7;
  const int xcd = orig & 7, lin = orig >> 3;
  const int wg = (xcd < rc ? xcd*(qc+1) : rc*(qc+1) + (xcd-rc)*qc) + lin;
  const int tm = wg / tiles_n, tn = wg % tiles_n;
  const size_t m0 = (size_t)tm * 128, n0 = (size_t)tn * 128;
  const int KT = K >> 6;

  const bf16* Ab = A  + m0 * K;
  const bf16* Bb = Bt + n0 * K;

  auto stage = [&](const bf16* gbase, bf16* ldsbase, int kt) {
#pragma unroll
    for (int j = 0; j < 2; ++j) {
      int lin2  = j*512 + tid;
      int prow  = lin2 >> 3;
      int pslot = lin2 & 7;
      int lslot = pslot ^ (prow & 7);
      const bf16* src = gbase + (size_t)prow * K + (size_t)kt*64 + lslot*8;
      bf16* dst = ldsbase + (size_t)(j*512 + (wid<<6))*8;
      gload16(src, dst);
    }
  };

  f32x4 acc[4][2] = {};

  for (int t = 0; t < KT; ++t) {
    __syncthreads();
    stage(Ab, As, t);
    stage(Bb, Bs, t);
    __syncthreads();
#pragma unroll
    for (int kk = 0; kk < 2; ++kk) {
      bf16x8 a[4], b[2];
#pragma unroll
      for (int m = 0; m < 4; ++m) {
        int row  = wr*64 + m*16 + lrow;
        int slot = (kk*4 + kgrp) ^ (lrow & 7);
        a[m] = *(const bf16x8*)&As[row*64 + slot*8];
      }
#pragma unroll
      for (int n = 0; n < 2; ++n) {
        int row  = wc*32 + n*16 + lrow;
        int slot = (kk*4 + kgrp) ^ (lrow & 7);
        b[n] = *(const bf16x8*)&Bs[row*64 + slot*8];
      }
#pragma unroll
      for (int m = 0; m < 4; ++m)
#pragma unroll
        for (int n = 0; n < 2; ++n)
          acc[m][n] = __builtin_amdgcn_mfma_f32_16x16x32_bf16(a[m], b[n], acc[m][n], 0, 0, 0);
    }
  }

#pragma unroll
  for (int m = 0; m < 4; ++m)
#pragma unroll
    for (int n = 0; n < 2; ++n) {
      int col = (int)n0 + wc*32 + n*16 + lrow;
      float bv = bias[col];
#pragma unroll
      for (int r = 0; r < 4; ++r) {
        int row = (int)m0 + wr*64 + m*16 + kgrp*4 + r;
        float x = acc[m][n][r] + bv;
        size_t idx = (size_t)row * N + col;
        if (epi == 1)      ((float*)outp)[idx] = x;
        else if (epi == 0) ((bf16*)outp)[idx]  = (bf16)x;
        else               ((bf16*)outp)[idx]  = (bf16)fast_gelu(x);
      }
    }
}

// ---------------- fused per-layer weight prep: 6 transposes + bias pack ----------------
__global__ __launch_bounds__(256) void weight_prep(
    const float* __restrict__ Wq, const float* __restrict__ Wk,
    const float* __restrict__ Wv, const float* __restrict__ Wo,
    const float* __restrict__ Wi, const float* __restrict__ Wf,
    const float* __restrict__ bq, const float* __restrict__ bk,
    const float* __restrict__ bv,
    bf16* __restrict__ wqkv, bf16* __restrict__ wot,
    bf16* __restrict__ wit,  bf16* __restrict__ wft,
    float* __restrict__ qkbias)
{
  int bid = blockIdx.x;
  if (bid >= 1728) {
    int i = (bid - 1728)*256 + threadIdx.x;
    if (i < QKV_)
      qkbias[i] = (i < 768) ? bq[i] : (i < 1536 ? bk[i-768] : bv[i-1536]);
    return;
  }
  const float* W; bf16* Wt; int K, N, t;
  if (bid < 576) {
    K = 768; N = 768;
    if      (bid < 144) { W = Wq; Wt = wqkv;             t = bid; }
    else if (bid < 288) { W = Wk; Wt = wqkv + 768*768;   t = bid - 144; }
    else if (bid < 432) { W = Wv; Wt = wqkv + 2*768*768; t = bid - 288; }
    else                { W = Wo; Wt = wot;              t = bid - 432; }
  } else if (bid < 1152) { W = Wi; Wt = wit; K = 768;  N = 3072; t = bid - 576; }
  else                   { W = Wf; Wt = wft; K = 3072; N = 768;  t = bid - 1152; }
  const int kt = K >> 6;
  const int k0 = (t % kt)*64, n0 = (t / kt)*64;

  __shared__ bf16 T[64][65];
  int tx = threadIdx.x & 63, ty = threadIdx.x >> 6;
#pragma unroll
  for (int j = 0; j < 16; ++j) {
    int kk = j*4 + ty;
    T[kk][tx] = (bf16)W[(size_t)(k0+kk)*N + n0 + tx];
  }
  __syncthreads();
#pragma unroll
  for (int j = 0; j < 16; ++j) {
    int nn = j*4 + ty;
    Wt[(size_t)(n0+nn)*K + k0 + tx] = T[tx][nn];
  }
}

// ---------------- block reductions ----------------
__device__ __forceinline__ void block_sum2(float& a, float& b, float* red) {
  int lane = threadIdx.x & 63, wid = threadIdx.x >> 6;
  for (int o = 32; o > 0; o >>= 1) { a += __shfl_xor(a, o); b += __shfl_xor(b, o); }
  if (lane == 0) { red[wid*2] = a; red[wid*2+1] = b; }
  __syncthreads();
  a = red[0] + red[2] + red[4] + red[6];
  b = red[1] + red[3] + red[5] + red[7];
  __syncthreads();
}

// ---------------- embedding + LN (bf16 residual out) ----------------
__global__ __launch_bounds__(256) void embed_ln(
    const int* __restrict__ ids, const float* __restrict__ we,
    const float* __restrict__ pe, const float* __restrict__ te,
    const float* __restrict__ gs, const float* __restrict__ gb,
    bf16* __restrict__ hb)
{
  __shared__ float red[8];
  int row = blockIdx.x;
  int s = row & (S_-1);
  int id = ids[row];
  int t = threadIdx.x;
  float x[3], sum = 0.f, sq = 0.f;
#pragma unroll
  for (int j = 0; j < 3; ++j) {
    int c = t + j*256;
    float v = we[(size_t)id*H_ + c] + pe[(size_t)s*H_ + c] + te[c];
    x[j] = v; sum += v; sq += v*v;
  }
  block_sum2(sum, sq, red);
  float mean = sum * (1.f/H_);
  float var  = sq  * (1.f/H_) - mean*mean;
  float rstd = rsqrtf(fmaxf(var, 0.f) + 1e-12f);
#pragma unroll
  for (int j = 0; j < 3; ++j) {
    int c = t + j*256;
    float y = (x[j]-mean)*rstd*gs[c] + gb[c];
    hb[(size_t)row*H_ + c] = (bf16)y;
  }
}

// ---------------- residual add + LN, all-bf16 streams ----------------
__global__ __launch_bounds__(256) void ln_res2(
    const bf16* __restrict__ t16, const bf16* __restrict__ res,
    const float* __restrict__ gs, const float* __restrict__ gb,
    bf16* __restrict__ out)
{
  __shared__ float red[2][2][2];
  int t = threadIdx.x;
  int rloc = t & 127, rsel = t >> 7, wir = (t >> 6) & 1;
  size_t row = (size_t)blockIdx.x*2 + rsel;
  const bf16* tp = t16 + row*H_;
  const bf16* rp = res + row*H_;
  float x[6];
  float sum = 0.f, sq = 0.f;
#pragma unroll
  for (int j = 0; j < 3; ++j) {
    int c = rloc*2 + j*256;
    bf16x2 a = *(const bf16x2*)&tp[c];
    bf16x2 b = *(const bf16x2*)&rp[c];
    float v0 = (float)a[0] + (float)b[0];
    float v1 = (float)a[1] + (float)b[1];
    x[j*2] = v0; x[j*2+1] = v1;
    sum += v0 + v1; sq += v0*v0 + v1*v1;
  }
  for (int o = 32; o > 0; o >>= 1) { sum += __shfl_xor(sum, o); sq += __shfl_xor(sq, o); }
  if ((t & 63) == 0) { red[rsel][wir][0] = sum; red[rsel][wir][1] = sq; }
  __syncthreads();
  sum = red[rsel][0][0] + red[rsel][1][0];
  sq  = red[rsel][0][1] + red[rsel][1][1];
  float mean = sum * (1.f/H_);
  float var  = sq  * (1.f/H_) - mean*mean;
  float rstd = rsqrtf(fmaxf(var, 0.f) + 1e-12f);
  bf16* op = out + row*H_;
#pragma unroll
  for (int j = 0; j < 3; ++j) {
    int c = rloc*2 + j*256;
    bf16x2 o2;
    o2[0] = (bf16)((x[j*2]   - mean)*rstd*gs[c]   + gb[c]);
    o2[1] = (bf16)((x[j*2+1] - mean)*rstd*gs[c+1] + gb[c+1]);
    *(bf16x2*)&op[c] = o2;
  }
}

// ---------------- fused attention: persistent balanced grid (r15, frozen) ----------------
__global__ __launch_bounds__(512, 2) void attn_kernel(
    const bf16* __restrict__ qkv, const float* __restrict__ mask,
    bf16* __restrict__ ctx)
{
  __shared__ bf16 Kl[S_*64];       // 65536 B, XOR-swizzled 16B slots
  __shared__ bf16 Vt[DH_*VST];     // 66048 B
  __shared__ float mk[S_];         //  2048 B
  __shared__ bf16 Pl[8][16*PST];   // 17408 B   total ~151 KB
  int tid = threadIdx.x, lane = tid & 63, wid = tid >> 6;
  int lrow = lane & 15, kgrp = lane >> 4;
  int cur_head = -1;

  bf16x8 onesv;
#pragma unroll
  for (int i = 0; i < 8; ++i) onesv[i] = (bf16)1.0f;

  for (int u = 0; u < 6; ++u) {
    int unit = blockIdx.x*6 + u;
    int hh = unit >> 2, pass = unit & 3;
    int b = hh / NH_, h = hh % NH_;
    const bf16* Qb = qkv + (size_t)(b*S_)*QKV_ + h*DH_;

    if (hh != cur_head) {
      __syncthreads();             // all waves done with prev head's tiles
      const bf16* Kb = qkv + (size_t)(b*S_)*QKV_ + H_   + h*DH_;
      const bf16* Vb = qkv + (size_t)(b*S_)*QKV_ + 2*H_ + h*DH_;
#pragma unroll
      for (int it = 0; it < 8; ++it) {
        int lin   = it*512 + tid;
        int prow  = lin >> 3;
        int pslot = lin & 7;
        int lslot = pslot ^ (prow & 7);
        gload16(&Kb[(size_t)prow*QKV_ + lslot*8],
                &Kl[(size_t)(it*512 + (wid<<6))*8]);
      }
      for (int it = 0; it < 8; ++it) {
        int slot = it*512 + tid;
        int s = slot >> 3, c8 = (slot & 7)*8;
        bf16x8 v = *(const bf16x8*)&Vb[(size_t)s*QKV_ + c8];
#pragma unroll
        for (int i = 0; i < 8; ++i) Vt[(c8+i)*VST + s] = v[i];
      }
      mk[tid] = mask[b*S_ + tid];  // 512 threads == S
      cur_head = hh;
      __syncthreads();             // drains vmcnt (gload16) + lgkm
    }

    int q0 = pass*128 + wid*16;
    bf16x8 qa[2];
#pragma unroll
    for (int kc = 0; kc < 2; ++kc) {
      qa[kc] = *(const bf16x8*)&Qb[(size_t)(q0 + lrow)*QKV_ + kc*32 + kgrp*8];
#pragma unroll
      for (int i = 0; i < 8; ++i)
        qa[kc][i] = (bf16)((float)qa[kc][i] * 0.125f);   // exact pow2
    }
    f32x4 O[4] = {};
    f32x4 O5 = {};                 // softmax denominator accumulator
    float mrun[4];
#pragma unroll
    for (int r = 0; r < 4; ++r) mrun[r] = -1e30f;

#pragma unroll 2
    for (int c0 = 0; c0 < S_; c0 += 64) {
      f32x4 Sf[4] = {};
      __builtin_amdgcn_s_setprio(1);
#pragma unroll
      for (int kc = 0; kc < 2; ++kc)
#pragma unroll
        for (int sn = 0; sn < 4; ++sn) {
          int row  = c0 + sn*16 + lrow;
          int slot = (kc*4 + kgrp) ^ (lrow & 7);
          bf16x8 kbv = *(const bf16x8*)&Kl[(size_t)row*64 + slot*8];
          Sf[sn] = __builtin_amdgcn_mfma_f32_16x16x32_bf16(qa[kc], kbv, Sf[sn], 0, 0, 0);
        }
      __builtin_amdgcn_s_setprio(0);

      float lm[4];
#pragma unroll
      for (int r = 0; r < 4; ++r)
        lm[r] = fmaxf(fmaxf(Sf[0][r], Sf[1][r]), fmaxf(Sf[2][r], Sf[3][r]));
      bool small = (lm[0] <= mrun[0]+8.f) && (lm[1] <= mrun[1]+8.f) &&
                   (lm[2] <= mrun[2]+8.f) && (lm[3] <= mrun[3]+8.f);
      bool skip = __all(small);
      float newm[4];
      if (skip) {
#pragma unroll
        for (int r = 0; r < 4; ++r) newm[r] = mrun[r];
      } else {
        float cmax[4];
#pragma unroll
        for (int r = 0; r < 4; ++r) cmax[r] = lm[r];
        for (int o = 1; o < 16; o <<= 1)
#pragma unroll
          for (int r = 0; r < 4; ++r) cmax[r] = fmaxf(cmax[r], __shfl_xor(cmax[r], o));
#pragma unroll
        for (int r = 0; r < 4; ++r) {
          newm[r] = fmaxf(mrun[r], cmax[r]);
          float fr = __expf(mrun[r] - newm[r]);
#pragma unroll
          for (int on = 0; on < 4; ++on) O[on][r] *= fr;
          O5[r] *= fr;
          mrun[r] = newm[r];
        }
      }
#pragma unroll
      for (int sn = 0; sn < 4; ++sn) {
        float mkv = mk[c0 + sn*16 + lrow];
#pragma unroll
        for (int r = 0; r < 4; ++r) {
          float e = __expf(Sf[sn][r] - newm[r]) * mkv;
          Pl[wid][(kgrp*4 + r)*PST + sn*16 + lrow] = (bf16)e;
        }
      }
      __builtin_amdgcn_s_setprio(1);
#pragma unroll
      for (int kc = 0; kc < 2; ++kc) {
        bf16x8 pa = *(const bf16x8*)&Pl[wid][lrow*PST + kc*32 + kgrp*8];
#pragma unroll
        for (int on = 0; on < 4; ++on) {
          bf16x8 vv = *(const bf16x8*)&Vt[(on*16 + lrow)*VST + c0 + kc*32 + kgrp*8];
          O[on] = __builtin_amdgcn_mfma_f32_16x16x32_bf16(pa, vv, O[on], 0, 0, 0);
        }
        O5 = __builtin_amdgcn_mfma_f32_16x16x32_bf16(pa, onesv, O5, 0, 0, 0);
      }
      __builtin_amdgcn_s_setprio(0);
    }
#pragma unroll
    for (int on = 0; on < 4; ++on)
#pragma unroll
      for (int r = 0; r < 4; ++r) {
        float val = O[on][r] / fmaxf(O5[r], 1e-9f);
        int q = q0 + kgrp*4 + r;
        ctx[(size_t)(b*S_ + q)*H_ + h*DH_ + on*16 + lrow] = (bf16)val;
      }
  }
}

// ---------------- pooling: partial (B*8 blocks, bf16 input) + final ----------------
__global__ __launch_bounds__(256) void pool_partial(
    const bf16* __restrict__ hb, const float* __restrict__ mask,
    float* __restrict__ part)
{
  int b = blockIdx.x >> 3, ch = blockIdx.x & 7;
  int t = threadIdx.x;
  float a0 = 0.f, a1 = 0.f, a2 = 0.f;
  for (int s = ch*64; s < ch*64 + 64; ++s) {
    float m = mask[b*S_ + s];
    const bf16* hp = &hb[((size_t)b*S_ + s)*H_];
    a0 += (float)hp[t]*m; a1 += (float)hp[t+256]*m; a2 += (float)hp[t+512]*m;
  }
  float* pp = &part[(size_t)(b*8 + ch)*H_];
  pp[t] = a0; pp[t+256] = a1; pp[t+512] = a2;
}

__global__ __launch_bounds__(256) void pool_final(
    const float* __restrict__ part, const float* __restrict__ mask,
    float* __restrict__ out)
{
  __shared__ float red[8];
  int b = blockIdx.x, t = threadIdx.x;
  float s0 = 0.f, s1 = 0.f, s2 = 0.f;
#pragma unroll
  for (int ch = 0; ch < 8; ++ch) {
    const float* pp = &part[(size_t)(b*8 + ch)*H_];
    s0 += pp[t]; s1 += pp[t+256]; s2 += pp[t+512];
  }
  float msum = mask[b*S_ + t] + mask[b*S_ + 256 + t];
  float dummy = 0.f;
  block_sum2(msum, dummy, red);
  float inv = 1.f / fmaxf(msum, 1e-6f);
  s0 *= inv; s1 *= inv; s2 *= inv;
  float nrm = s0*s0 + s1*s1 + s2*s2;
  dummy = 0.f;
  block_sum2(nrm, dummy, red);
  float rn = 1.f / fmaxf(sqrtf(nrm), 1e-12f);
  out[b*H_ + t]       = s0*rn;
  out[b*H_ + t + 256] = s1*rn;
  out[b*H_ + t + 512] = s2*rn;
}

// ---------------- host driver ----------------
extern "C" void kernel_launch(void* const* d_in, const int* in_sizes, int n_in,
                              void* d_out, int out_size, void* d_ws, size_t ws_size,
                              hipStream_t stream)
{
  const int*   ids  = (const int*)  d_in[0];
  const float* mask = (const float*)d_in[1];
  const float* we   = (const float*)d_in[2];
  const float* pe   = (const float*)d_in[3];
  const float* te   = (const float*)d_in[4];
  const float* les  = (const float*)d_in[5];
  const float* leb  = (const float*)d_in[6];
  const float* Wq   = (const float*)d_in[7];
  const float* bq   = (const float*)d_in[8];
  const float* Wk   = (const float*)d_in[9];
  const float* bk   = (const float*)d_in[10];
  const float* Wv   = (const float*)d_in[11];
  const float* bv   = (const float*)d_in[12];
  const float* Wo   = (const float*)d_in[13];
  const float* bo   = (const float*)d_in[14];
  const float* l1s  = (const float*)d_in[15];
  const float* l1b  = (const float*)d_in[16];
  const float* Wi   = (const float*)d_in[17];
  const float* bi   = (const float*)d_in[18];
  const float* Wf   = (const float*)d_in[19];
  const float* bfp  = (const float*)d_in[20];
  const float* l2s  = (const float*)d_in[21];
  const float* l2b  = (const float*)d_in[22];

  char* p = (char*)d_ws;
  auto alloc = [&](size_t bytes) { char* q = p; p += (bytes + 255) & ~(size_t)255; return q; };
  bf16*  wqkv = (bf16*) alloc((size_t)QKV_*H_*2);
  bf16*  wot  = (bf16*) alloc((size_t)H_*H_*2);
  bf16*  wit  = (bf16*) alloc((size_t)H_*FF_*2);
  bf16*  wft  = (bf16*) alloc((size_t)H_*FF_*2);
  float* qkbias=(float*)alloc((size_t)QKV_*4);
  bf16*  hb   = (bf16*) alloc((size_t)M_*H_*2);
  bf16*  ab   = (bf16*) alloc((size_t)M_*H_*2);
  bf16*  tmpb = (bf16*) alloc((size_t)M_*H_*2);
  bf16*  qkvb = (bf16*) alloc((size_t)M_*QKV_*2);
  bf16*  cxb  = (bf16*) alloc((size_t)M_*H_*2);
  bf16*  inb  = (bf16*) alloc((size_t)M_*FF_*2);
  float* part = (float*)alloc((size_t)B_*8*H_*4);

  embed_ln<<<M_, 256, 0, stream>>>(ids, we, pe, te, les, leb, hb);

  for (int l = 0; l < L_; ++l) {
    size_t wsq = (size_t)l*H_*H_;
    weight_prep<<<1737, 256, 0, stream>>>(
        Wq + wsq, Wk + wsq, Wv + wsq, Wo + wsq,
        Wi + (size_t)l*H_*FF_, Wf + (size_t)l*FF_*H_,
        bq + l*H_, bk + l*H_, bv + l*H_,
        wqkv, wot, wit, wft, qkbias);

    gemm128<<<128*(QKV_/128), 512, 0, stream>>>(hb,  wqkv, qkbias,      qkvb, QKV_, H_,  QKV_/128, 0);
    attn_kernel<<<256, 512, 0, stream>>>(qkvb, mask, cxb);
    gemm128<<<128*(H_/128),  512, 0, stream>>>(cxb, wot, bo  + l*H_,  tmpb, H_,  H_,  H_/128,  0);
    ln_res2<<<M_/2, 256, 0, stream>>>(tmpb, hb, l1s + l*H_, l1b + l*H_, ab);
    gemm128<<<128*(FF_/128), 512, 0, stream>>>(ab,  wit, bi  + l*FF_, inb,  FF_, H_,  FF_/128, 2);
    gemm128<<<128*(H_/128),  512, 0, stream>>>(inb, wft, bfp + l*H_,  tmpb, H_,  FF_, H_/128,  0);
    ln_res2<<<M_/2, 256, 0, stream>>>(tmpb, ab, l2s + l*H_, l2b + l*H_, hb);
  }

  pool_partial<<<B_*8, 256, 0, stream>>>(hb, mask, part);
  pool_final<<<B_, 256, 0, stream>>>(part, mask, (float*)d_out);
}

// Round 19
// 4658.006 us; speedup vs baseline: 1.1338x; 1.0096x over previous
//
#include <hip/hip_runtime.h>
#include <hip/hip_bf16.h>
#include <math.h>

typedef __bf16 bf16;
typedef __bf16 bf16x2 __attribute__((ext_vector_type(2)));
typedef __bf16 bf16x8 __attribute__((ext_vector_type(8)));
typedef float  f32x4  __attribute__((ext_vector_type(4)));

#define B_  32
#define S_  512
#define H_  768
#define NH_ 12
#define DH_ 64
#define FF_ 3072
#define L_  12
#define M_  (B_*S_)
#define QKV_ 2304   // packed q|k|v row stride

// padded LDS strides (attention V/P tiles; K XOR-swizzled, unpadded)
#define VST 516
#define PST 68

// ---- async global->LDS, 16B per lane; lds base must be wave-uniform ----
__device__ __forceinline__ void gload16(const bf16* g, bf16* l) {
  __builtin_amdgcn_global_load_lds(
      (const __attribute__((address_space(1))) void*)g,
      (__attribute__((address_space(3))) void*)l, 16, 0, 0);
}

// ---- native 2^x (v_exp_f32); exp2-domain softmax avoids __expf's hidden mul ----
__device__ __forceinline__ float exp2_fast(float x) {
  float r;
  asm("v_exp_f32 %0, %1" : "=v"(r) : "v"(x));
  return r;
}

// ---- fast exact-GELU: Abramowitz-Stegun 7.1.26 erf, |err| < 1.5e-7 ----
__device__ __forceinline__ float fast_gelu(float x) {
  float z = x * 0.70710678118f;
  float s = fabsf(z);
  float t = __builtin_amdgcn_rcpf(1.0f + 0.3275911f * s);
  float p = t*(0.254829592f + t*(-0.284496736f + t*(1.421413741f +
            t*(-1.453152027f + t*1.061405429f))));
  float e = p * __expf(-s*s);          // = 1 - erf(s)
  float erfv = copysignf(1.0f - e, z);
  return 0.5f * x * (1.0f + erfv);
}

// =================== 128x128 GEMM, 8 waves (FROZEN — r16 known-good) ===================
__global__ __launch_bounds__(512, 4) void gemm128(
    const bf16* __restrict__ A, const bf16* __restrict__ Bt,
    const float* __restrict__ bias, void* __restrict__ outp,
    int N, int K, int tiles_n, int epi)
{
  __shared__ bf16 As[128*64];   // 16 KB
  __shared__ bf16 Bs[128*64];   // 16 KB
  const int tid  = threadIdx.x;
  const int lane = tid & 63, wid = tid >> 6;
  const int wr = wid >> 2, wc = wid & 3;          // 2 x 4 wave grid, 64x32 per wave
  const int lrow = lane & 15, kgrp = lane >> 4;

  // bijective XCD swizzle (m204)
  const int nwg = gridDim.x, orig = blockIdx.x;
  const int qc = nwg >> 3, rc = nwg & 7;
  const int xcd = orig & 7, lin = orig >> 3;
  const int wg = (xcd < rc ? xcd*(qc+1) : rc*(qc+1) + (xcd-rc)*qc) + lin;
  const int tm = wg / tiles_n, tn = wg % tiles_n;
  const size_t m0 = (size_t)tm * 128, n0 = (size_t)tn * 128;
  const int KT = K >> 6;

  const bf16* Ab = A  + m0 * K;
  const bf16* Bb = Bt + n0 * K;

  auto stage = [&](const bf16* gbase, bf16* ldsbase, int kt) {
#pragma unroll
    for (int j = 0; j < 2; ++j) {
      int lin2  = j*512 + tid;
      int prow  = lin2 >> 3;
      int pslot = lin2 & 7;
      int lslot = pslot ^ (prow & 7);
      const bf16* src = gbase + (size_t)prow * K + (size_t)kt*64 + lslot*8;
      bf16* dst = ldsbase + (size_t)(j*512 + (wid<<6))*8;
      gload16(src, dst);
    }
  };

  f32x4 acc[4][2] = {};

  for (int t = 0; t < KT; ++t) {
    __syncthreads();
    stage(Ab, As, t);
    stage(Bb, Bs, t);
    __syncthreads();
#pragma unroll
    for (int kk = 0; kk < 2; ++kk) {
      bf16x8 a[4], b[2];
#pragma unroll
      for (int m = 0; m < 4; ++m) {
        int row  = wr*64 + m*16 + lrow;
        int slot = (kk*4 + kgrp) ^ (lrow & 7);
        a[m] = *(const bf16x8*)&As[row*64 + slot*8];
      }
#pragma unroll
      for (int n = 0; n < 2; ++n) {
        int row  = wc*32 + n*16 + lrow;
        int slot = (kk*4 + kgrp) ^ (lrow & 7);
        b[n] = *(const bf16x8*)&Bs[row*64 + slot*8];
      }
#pragma unroll
      for (int m = 0; m < 4; ++m)
#pragma unroll
        for (int n = 0; n < 2; ++n)
          acc[m][n] = __builtin_amdgcn_mfma_f32_16x16x32_bf16(a[m], b[n], acc[m][n], 0, 0, 0);
    }
  }

#pragma unroll
  for (int m = 0; m < 4; ++m)
#pragma unroll
    for (int n = 0; n < 2; ++n) {
      int col = (int)n0 + wc*32 + n*16 + lrow;
      float bv = bias[col];
#pragma unroll
      for (int r = 0; r < 4; ++r) {
        int row = (int)m0 + wr*64 + m*16 + kgrp*4 + r;
        float x = acc[m][n][r] + bv;
        size_t idx = (size_t)row * N + col;
        if (epi == 1)      ((float*)outp)[idx] = x;
        else if (epi == 0) ((bf16*)outp)[idx]  = (bf16)x;
        else               ((bf16*)outp)[idx]  = (bf16)fast_gelu(x);
      }
    }
}

// ---------------- fused per-layer weight prep: 6 transposes + bias pack ----------------
__global__ __launch_bounds__(256) void weight_prep(
    const float* __restrict__ Wq, const float* __restrict__ Wk,
    const float* __restrict__ Wv, const float* __restrict__ Wo,
    const float* __restrict__ Wi, const float* __restrict__ Wf,
    const float* __restrict__ bq, const float* __restrict__ bk,
    const float* __restrict__ bv,
    bf16* __restrict__ wqkv, bf16* __restrict__ wot,
    bf16* __restrict__ wit,  bf16* __restrict__ wft,
    float* __restrict__ qkbias)
{
  int bid = blockIdx.x;
  if (bid >= 1728) {
    int i = (bid - 1728)*256 + threadIdx.x;
    if (i < QKV_)
      qkbias[i] = (i < 768) ? bq[i] : (i < 1536 ? bk[i-768] : bv[i-1536]);
    return;
  }
  const float* W; bf16* Wt; int K, N, t;
  if (bid < 576) {
    K = 768; N = 768;
    if      (bid < 144) { W = Wq; Wt = wqkv;             t = bid; }
    else if (bid < 288) { W = Wk; Wt = wqkv + 768*768;   t = bid - 144; }
    else if (bid < 432) { W = Wv; Wt = wqkv + 2*768*768; t = bid - 288; }
    else                { W = Wo; Wt = wot;              t = bid - 432; }
  } else if (bid < 1152) { W = Wi; Wt = wit; K = 768;  N = 3072; t = bid - 576; }
  else                   { W = Wf; Wt = wft; K = 3072; N = 768;  t = bid - 1152; }
  const int kt = K >> 6;
  const int k0 = (t % kt)*64, n0 = (t / kt)*64;

  __shared__ bf16 T[64][65];
  int tx = threadIdx.x & 63, ty = threadIdx.x >> 6;
#pragma unroll
  for (int j = 0; j < 16; ++j) {
    int kk = j*4 + ty;
    T[kk][tx] = (bf16)W[(size_t)(k0+kk)*N + n0 + tx];
  }
  __syncthreads();
#pragma unroll
  for (int j = 0; j < 16; ++j) {
    int nn = j*4 + ty;
    Wt[(size_t)(n0+nn)*K + k0 + tx] = T[tx][nn];
  }
}

// ---------------- block reductions ----------------
__device__ __forceinline__ void block_sum2(float& a, float& b, float* red) {
  int lane = threadIdx.x & 63, wid = threadIdx.x >> 6;
  for (int o = 32; o > 0; o >>= 1) { a += __shfl_xor(a, o); b += __shfl_xor(b, o); }
  if (lane == 0) { red[wid*2] = a; red[wid*2+1] = b; }
  __syncthreads();
  a = red[0] + red[2] + red[4] + red[6];
  b = red[1] + red[3] + red[5] + red[7];
  __syncthreads();
}

// ---------------- embedding + LN (bf16 residual out) ----------------
__global__ __launch_bounds__(256) void embed_ln(
    const int* __restrict__ ids, const float* __restrict__ we,
    const float* __restrict__ pe, const float* __restrict__ te,
    const float* __restrict__ gs, const float* __restrict__ gb,
    bf16* __restrict__ hb)
{
  __shared__ float red[8];
  int row = blockIdx.x;
  int s = row & (S_-1);
  int id = ids[row];
  int t = threadIdx.x;
  float x[3], sum = 0.f, sq = 0.f;
#pragma unroll
  for (int j = 0; j < 3; ++j) {
    int c = t + j*256;
    float v = we[(size_t)id*H_ + c] + pe[(size_t)s*H_ + c] + te[c];
    x[j] = v; sum += v; sq += v*v;
  }
  block_sum2(sum, sq, red);
  float mean = sum * (1.f/H_);
  float var  = sq  * (1.f/H_) - mean*mean;
  float rstd = rsqrtf(fmaxf(var, 0.f) + 1e-12f);
#pragma unroll
  for (int j = 0; j < 3; ++j) {
    int c = t + j*256;
    float y = (x[j]-mean)*rstd*gs[c] + gb[c];
    hb[(size_t)row*H_ + c] = (bf16)y;
  }
}

// ---------------- residual add + LN, all-bf16 streams ----------------
__global__ __launch_bounds__(256) void ln_res2(
    const bf16* __restrict__ t16, const bf16* __restrict__ res,
    const float* __restrict__ gs, const float* __restrict__ gb,
    bf16* __restrict__ out)
{
  __shared__ float red[2][2][2];
  int t = threadIdx.x;
  int rloc = t & 127, rsel = t >> 7, wir = (t >> 6) & 1;
  size_t row = (size_t)blockIdx.x*2 + rsel;
  const bf16* tp = t16 + row*H_;
  const bf16* rp = res + row*H_;
  float x[6];
  float sum = 0.f, sq = 0.f;
#pragma unroll
  for (int j = 0; j < 3; ++j) {
    int c = rloc*2 + j*256;
    bf16x2 a = *(const bf16x2*)&tp[c];
    bf16x2 b = *(const bf16x2*)&rp[c];
    float v0 = (float)a[0] + (float)b[0];
    float v1 = (float)a[1] + (float)b[1];
    x[j*2] = v0; x[j*2+1] = v1;
    sum += v0 + v1; sq += v0*v0 + v1*v1;
  }
  for (int o = 32; o > 0; o >>= 1) { sum += __shfl_xor(sum, o); sq += __shfl_xor(sq, o); }
  if ((t & 63) == 0) { red[rsel][wir][0] = sum; red[rsel][wir][1] = sq; }
  __syncthreads();
  sum = red[rsel][0][0] + red[rsel][1][0];
  sq  = red[rsel][0][1] + red[rsel][1][1];
  float mean = sum * (1.f/H_);
  float var  = sq  * (1.f/H_) - mean*mean;
  float rstd = rsqrtf(fmaxf(var, 0.f) + 1e-12f);
  bf16* op = out + row*H_;
#pragma unroll
  for (int j = 0; j < 3; ++j) {
    int c = rloc*2 + j*256;
    bf16x2 o2;
    o2[0] = (bf16)((x[j*2]   - mean)*rstd*gs[c]   + gb[c]);
    o2[1] = (bf16)((x[j*2+1] - mean)*rstd*gs[c+1] + gb[c+1]);
    *(bf16x2*)&op[c] = o2;
  }
}

// ---------------- fused attention: persistent balanced grid ----------------
// r19: VALU diet. (a) exp2-domain softmax: log2e folded into the existing
// Q-scale multiply (0.125*log2e) -> exp is a bare v_exp_f32 (2^x), removing
// __expf's 16 hidden v_muls per chunk. Defer threshold 8*log2e.
// (b) masked-V: V rows pre-multiplied by mask at staging; denominator O5 uses
// a bf16 mask-fragment (broadcast LDS read) instead of ones -> the 16 mask
// muls + 4 mask loads leave the inner loop. Denominator = sum(P*m) exactly.
__global__ __launch_bounds__(512, 2) void attn_kernel(
    const bf16* __restrict__ qkv, const float* __restrict__ mask,
    bf16* __restrict__ ctx)
{
  __shared__ bf16 Kl[S_*64];       // 65536 B, XOR-swizzled 16B slots
  __shared__ bf16 Vt[DH_*VST];     // 66048 B (pre-masked V, transposed)
  __shared__ bf16 mkb[S_];         //  1024 B (bf16 mask)
  __shared__ bf16 Pl[8][16*PST];   // 17408 B   total ~146.5 KB
  int tid = threadIdx.x, lane = tid & 63, wid = tid >> 6;
  int lrow = lane & 15, kgrp = lane >> 4;
  int cur_head = -1;

  for (int u = 0; u < 6; ++u) {
    int unit = blockIdx.x*6 + u;
    int hh = unit >> 2, pass = unit & 3;
    int b = hh / NH_, h = hh % NH_;
    const bf16* Qb = qkv + (size_t)(b*S_)*QKV_ + h*DH_;

    if (hh != cur_head) {
      __syncthreads();             // all waves done with prev head's tiles
      const bf16* Kb = qkv + (size_t)(b*S_)*QKV_ + H_   + h*DH_;
      const bf16* Vb = qkv + (size_t)(b*S_)*QKV_ + 2*H_ + h*DH_;
#pragma unroll
      for (int it = 0; it < 8; ++it) {
        int lin   = it*512 + tid;
        int prow  = lin >> 3;
        int pslot = lin & 7;
        int lslot = pslot ^ (prow & 7);
        gload16(&Kb[(size_t)prow*QKV_ + lslot*8],
                &Kl[(size_t)(it*512 + (wid<<6))*8]);
      }
      for (int it = 0; it < 8; ++it) {
        int slot = it*512 + tid;
        int s = slot >> 3, c8 = (slot & 7)*8;
        float mval = mask[b*S_ + s];
        bf16x8 v = *(const bf16x8*)&Vb[(size_t)s*QKV_ + c8];
#pragma unroll
        for (int i = 0; i < 8; ++i) Vt[(c8+i)*VST + s] = (bf16)((float)v[i] * mval);
      }
      mkb[tid] = (bf16)mask[b*S_ + tid];   // 512 threads == S
      cur_head = hh;
      __syncthreads();             // drains vmcnt (gload16) + lgkm
    }

    int q0 = pass*128 + wid*16;
    bf16x8 qa[2];
#pragma unroll
    for (int kc = 0; kc < 2; ++kc) {
      qa[kc] = *(const bf16x8*)&Qb[(size_t)(q0 + lrow)*QKV_ + kc*32 + kgrp*8];
#pragma unroll
      for (int i = 0; i < 8; ++i)
        qa[kc][i] = (bf16)((float)qa[kc][i] * 0.18033688f);  // 0.125 * log2(e)
    }
    f32x4 O[4] = {};
    f32x4 O5 = {};                 // denominator accumulator (sum P*mask)
    float mrun[4];
#pragma unroll
    for (int r = 0; r < 4; ++r) mrun[r] = -1e30f;

#pragma unroll 2
    for (int c0 = 0; c0 < S_; c0 += 64) {
      f32x4 Sf[4] = {};
      __builtin_amdgcn_s_setprio(1);
#pragma unroll
      for (int kc = 0; kc < 2; ++kc)
#pragma unroll
        for (int sn = 0; sn < 4; ++sn) {
          int row  = c0 + sn*16 + lrow;
          int slot = (kc*4 + kgrp) ^ (lrow & 7);
          bf16x8 kbv = *(const bf16x8*)&Kl[(size_t)row*64 + slot*8];
          Sf[sn] = __builtin_amdgcn_mfma_f32_16x16x32_bf16(qa[kc], kbv, Sf[sn], 0, 0, 0);
        }
      __builtin_amdgcn_s_setprio(0);

      // lane-local maxima only (fast path needs no cross-lane reduce)
      float lm[4];
#pragma unroll
      for (int r = 0; r < 4; ++r)
        lm[r] = fmaxf(fmaxf(Sf[0][r], Sf[1][r]), fmaxf(Sf[2][r], Sf[3][r]));
      bool small = (lm[0] <= mrun[0]+11.5415603f) && (lm[1] <= mrun[1]+11.5415603f) &&
                   (lm[2] <= mrun[2]+11.5415603f) && (lm[3] <= mrun[3]+11.5415603f);
      bool skip = __all(small);
      float newm[4];
      if (skip) {
#pragma unroll
        for (int r = 0; r < 4; ++r) newm[r] = mrun[r];
      } else {
        float cmax[4];
#pragma unroll
        for (int r = 0; r < 4; ++r) cmax[r] = lm[r];
        for (int o = 1; o < 16; o <<= 1)
#pragma unroll
          for (int r = 0; r < 4; ++r) cmax[r] = fmaxf(cmax[r], __shfl_xor(cmax[r], o));
#pragma unroll
        for (int r = 0; r < 4; ++r) {
          newm[r] = fmaxf(mrun[r], cmax[r]);
          float fr = exp2_fast(mrun[r] - newm[r]);
#pragma unroll
          for (int on = 0; on < 4; ++on) O[on][r] *= fr;
          O5[r] *= fr;
          mrun[r] = newm[r];
        }
      }
#pragma unroll
      for (int sn = 0; sn < 4; ++sn)
#pragma unroll
        for (int r = 0; r < 4; ++r) {
          float e = exp2_fast(Sf[sn][r] - newm[r]);     // unmasked P
          Pl[wid][(kgrp*4 + r)*PST + sn*16 + lrow] = (bf16)e;
        }
      __builtin_amdgcn_s_setprio(1);
#pragma unroll
      for (int kc = 0; kc < 2; ++kc) {
        bf16x8 pa  = *(const bf16x8*)&Pl[wid][lrow*PST + kc*32 + kgrp*8];
        bf16x8 mfr = *(const bf16x8*)&mkb[c0 + kc*32 + kgrp*8];  // broadcast read
#pragma unroll
        for (int on = 0; on < 4; ++on) {
          bf16x8 vv = *(const bf16x8*)&Vt[(on*16 + lrow)*VST + c0 + kc*32 + kgrp*8];
          O[on] = __builtin_amdgcn_mfma_f32_16x16x32_bf16(pa, vv, O[on], 0, 0, 0);
        }
        O5 = __builtin_amdgcn_mfma_f32_16x16x32_bf16(pa, mfr, O5, 0, 0, 0);
      }
      __builtin_amdgcn_s_setprio(0);
    }
#pragma unroll
    for (int on = 0; on < 4; ++on)
#pragma unroll
      for (int r = 0; r < 4; ++r) {
        float val = O[on][r] / fmaxf(O5[r], 1e-9f);
        int q = q0 + kgrp*4 + r;
        ctx[(size_t)(b*S_ + q)*H_ + h*DH_ + on*16 + lrow] = (bf16)val;
      }
  }
}

// ---------------- pooling: partial (B*8 blocks, bf16 input) + final ----------------
__global__ __launch_bounds__(256) void pool_partial(
    const bf16* __restrict__ hb, const float* __restrict__ mask,
    float* __restrict__ part)
{
  int b = blockIdx.x >> 3, ch = blockIdx.x & 7;
  int t = threadIdx.x;
  float a0 = 0.f, a1 = 0.f, a2 = 0.f;
  for (int s = ch*64; s < ch*64 + 64; ++s) {
    float m = mask[b*S_ + s];
    const bf16* hp = &hb[((size_t)b*S_ + s)*H_];
    a0 += (float)hp[t]*m; a1 += (float)hp[t+256]*m; a2 += (float)hp[t+512]*m;
  }
  float* pp = &part[(size_t)(b*8 + ch)*H_];
  pp[t] = a0; pp[t+256] = a1; pp[t+512] = a2;
}

__global__ __launch_bounds__(256) void pool_final(
    const float* __restrict__ part, const float* __restrict__ mask,
    float* __restrict__ out)
{
  __shared__ float red[8];
  int b = blockIdx.x, t = threadIdx.x;
  float s0 = 0.f, s1 = 0.f, s2 = 0.f;
#pragma unroll
  for (int ch = 0; ch < 8; ++ch) {
    const float* pp = &part[(size_t)(b*8 + ch)*H_];
    s0 += pp[t]; s1 += pp[t+256]; s2 += pp[t+512];
  }
  float msum = mask[b*S_ + t] + mask[b*S_ + 256 + t];
  float dummy = 0.f;
  block_sum2(msum, dummy, red);
  float inv = 1.f / fmaxf(msum, 1e-6f);
  s0 *= inv; s1 *= inv; s2 *= inv;
  float nrm = s0*s0 + s1*s1 + s2*s2;
  dummy = 0.f;
  block_sum2(nrm, dummy, red);
  float rn = 1.f / fmaxf(sqrtf(nrm), 1e-12f);
  out[b*H_ + t]       = s0*rn;
  out[b*H_ + t + 256] = s1*rn;
  out[b*H_ + t + 512] = s2*rn;
}

// ---------------- host driver ----------------
extern "C" void kernel_launch(void* const* d_in, const int* in_sizes, int n_in,
                              void* d_out, int out_size, void* d_ws, size_t ws_size,
                              hipStream_t stream)
{
  const int*   ids  = (const int*)  d_in[0];
  const float* mask = (const float*)d_in[1];
  const float* we   = (const float*)d_in[2];
  const float* pe   = (const float*)d_in[3];
  const float* te   = (const float*)d_in[4];
  const float* les  = (const float*)d_in[5];
  const float* leb  = (const float*)d_in[6];
  const float* Wq   = (const float*)d_in[7];
  const float* bq   = (const float*)d_in[8];
  const float* Wk   = (const float*)d_in[9];
  const float* bk   = (const float*)d_in[10];
  const float* Wv   = (const float*)d_in[11];
  const float* bv   = (const float*)d_in[12];
  const float* Wo   = (const float*)d_in[13];
  const float* bo   = (const float*)d_in[14];
  const float* l1s  = (const float*)d_in[15];
  const float* l1b  = (const float*)d_in[16];
  const float* Wi   = (const float*)d_in[17];
  const float* bi   = (const float*)d_in[18];
  const float* Wf   = (const float*)d_in[19];
  const float* bfp  = (const float*)d_in[20];
  const float* l2s  = (const float*)d_in[21];
  const float* l2b  = (const float*)d_in[22];

  char* p = (char*)d_ws;
  auto alloc = [&](size_t bytes) { char* q = p; p += (bytes + 255) & ~(size_t)255; return q; };
  bf16*  wqkv = (bf16*) alloc((size_t)QKV_*H_*2);
  bf16*  wot  = (bf16*) alloc((size_t)H_*H_*2);
  bf16*  wit  = (bf16*) alloc((size_t)H_*FF_*2);
  bf16*  wft  = (bf16*) alloc((size_t)H_*FF_*2);
  float* qkbias=(float*)alloc((size_t)QKV_*4);
  bf16*  hb   = (bf16*) alloc((size_t)M_*H_*2);
  bf16*  ab   = (bf16*) alloc((size_t)M_*H_*2);
  bf16*  tmpb = (bf16*) alloc((size_t)M_*H_*2);
  bf16*  qkvb = (bf16*) alloc((size_t)M_*QKV_*2);
  bf16*  cxb  = (bf16*) alloc((size_t)M_*H_*2);
  bf16*  inb  = (bf16*) alloc((size_t)M_*FF_*2);
  float* part = (float*)alloc((size_t)B_*8*H_*4);

  embed_ln<<<M_, 256, 0, stream>>>(ids, we, pe, te, les, leb, hb);

  for (int l = 0; l < L_; ++l) {
    size_t wsq = (size_t)l*H_*H_;
    weight_prep<<<1737, 256, 0, stream>>>(
        Wq + wsq, Wk + wsq, Wv + wsq, Wo + wsq,
        Wi + (size_t)l*H_*FF_, Wf + (size_t)l*FF_*H_,
        bq + l*H_, bk + l*H_, bv + l*H_,
        wqkv, wot, wit, wft, qkbias);

    gemm128<<<128*(QKV_/128), 512, 0, stream>>>(hb,  wqkv, qkbias,      qkvb, QKV_, H_,  QKV_/128, 0);
    attn_kernel<<<256, 512, 0, stream>>>(qkvb, mask, cxb);
    gemm128<<<128*(H_/128),  512, 0, stream>>>(cxb, wot, bo  + l*H_,  tmpb, H_,  H_,  H_/128,  0);
    ln_res2<<<M_/2, 256, 0, stream>>>(tmpb, hb, l1s + l*H_, l1b + l*H_, ab);
    gemm128<<<128*(FF_/128), 512, 0, stream>>>(ab,  wit, bi  + l*FF_, inb,  FF_, H_,  FF_/128, 2);
    gemm128<<<128*(H_/128),  512, 0, stream>>>(inb, wft, bfp + l*H_,  tmpb, H_,  FF_, H_/128,  0);
    ln_res2<<<M_/2, 256, 0, stream>>>(tmpb, ab, l2s + l*H_, l2b + l*H_, hb);
  }

  pool_partial<<<B_*8, 256, 0, stream>>>(hb, mask, part);
  pool_final<<<B_, 256, 0, stream>>>(part, mask, (float*)d_out);
}